// Round 2
// baseline (332.159 us; speedup 1.0000x reference)
//
#include <hip/hip_runtime.h>

#define HOG_PI 3.14159265358979323846f

// Two workgroups per image: half 0 -> rows 0..143 (cell rows 0..8, blocks by 0..7),
// half 1 -> rows 128..255 (cell rows 8..15, blocks by 8..14). 16 rows duplicated.
// Thread map: xq = t&31 (float4 column), yg = t>>5 (row group); rows stride 8.
// All global loads coalesced (wave reads contiguous 512B row segments).
__global__ __launch_bounds__(256, 4) void hog_kernel(
    const float* __restrict__ img, const int* __restrict__ targets,
    const int* __restrict__ camid, float* __restrict__ out, int B) {
  const int bb = blockIdx.x;
  const int b = bb >> 1;
  const int half = bb & 1;
  const int t = threadIdx.x;
  const float* im = img + (size_t)b * (3 * 256 * 128);

  __shared__ float part[256][9];    // thread-private partial histograms
  __shared__ float cellh[9][8][9];  // local cell rows (9 top / 8 bottom), 8 cols, 9 bins

#pragma unroll
  for (int k = 0; k < 9; ++k) part[t][k] = 0.0f;
  for (int i = t; i < 9 * 8 * 9; i += 256) ((float*)cellh)[i] = 0.0f;
  __syncthreads();

  const int xq = t & 31;   // float4 column 0..31
  const int yg = t >> 5;   // 0..7
  const int x0 = xq * 4;
  const int cx = xq >> 2;  // cell column 0..7
  const int rbase = half ? 128 : 0;
  const int nj = half ? 16 : 18;

  for (int j = 0; j < nj; ++j) {
    const int y = rbase + yg + 8 * j;
    const int ym = (y == 0) ? 0 : y - 1;
    const int yp = (y == 255) ? 255 : y + 1;
    float dxv[3][4], dyv[3][4];
#pragma unroll
    for (int c = 0; c < 3; ++c) {
      const float* rc = im + c * 32768 + y * 128;
      const float* ru = im + c * 32768 + ym * 128;
      const float* rd = im + c * 32768 + yp * 128;
      const float4 cc = *(const float4*)(rc + x0);
      const float4 uu = *(const float4*)(ru + x0);
      const float4 dd = *(const float4*)(rd + x0);
      const float lf = (x0 == 0) ? cc.x : rc[x0 - 1];
      const float rf = (x0 == 124) ? cc.w : rc[x0 + 4];
      dxv[c][0] = cc.y - lf;
      dxv[c][1] = cc.z - cc.x;
      dxv[c][2] = cc.w - cc.y;
      dxv[c][3] = rf - cc.z;
      dyv[c][0] = dd.x - uu.x;
      dyv[c][1] = dd.y - uu.y;
      dyv[c][2] = dd.z - uu.z;
      dyv[c][3] = dd.w - uu.w;
    }
#pragma unroll
    for (int i = 0; i < 4; ++i) {
      // channel argmax, first-max wins on ties (strict >)
      float dxs = dxv[0][i], dys = dyv[0][i];
      float g = dxs * dxs + dys * dys;
      const float g1 = dxv[1][i] * dxv[1][i] + dyv[1][i] * dyv[1][i];
      if (g1 > g) { dxs = dxv[1][i]; dys = dyv[1][i]; g = g1; }
      const float g2 = dxv[2][i] * dxv[2][i] + dyv[2][i] * dyv[2][i];
      if (g2 > g) { dxs = dxv[2][i]; dys = dyv[2][i]; g = g2; }
      const float mag = sqrtf(g);
      float ang = atan2f(dys, dxs);
      if (ang < 0.0f) ang += HOG_PI;  // mod pi -> [0, pi)
      const float pos = ang * (9.0f / HOG_PI) - 0.5f;
      const float bf = floorf(pos);
      const float frac = pos - bf;
      const int b0 = (int)bf;  // in [-1, 8]
      const int b0i = (b0 < 0) ? 8 : b0;
      const int b1i = (b0i == 8) ? 0 : b0i + 1;
      atomicAdd(&part[t][b0i], mag * (1.0f - frac));
      atomicAdd(&part[t][b1i], mag * frac);
    }
    if (j & 1) {  // finished a 16-row cell band: flush private row -> cell hist
      const int band = j >> 1;
#pragma unroll
      for (int k = 0; k < 9; ++k) {
        atomicAdd(&cellh[band][cx][k], part[t][k]);
        part[t][k] = 0.0f;
      }
    }
  }
  __syncthreads();

  float* outF = out + (size_t)b * 4096;
  const int nby = half ? 7 : 8;
  if (t < nby * 7) {
    const int byl = t / 7;
    const int bx = t - byl * 7;
    const int byg = half ? (8 + byl) : byl;
    float v[36];
#pragma unroll
    for (int q = 0; q < 4; ++q) {
      const int cy = byl + (q >> 1);
      const int cc = bx + (q & 1);
#pragma unroll
      for (int k = 0; k < 9; ++k) v[q * 9 + k] = cellh[cy][cc][k];
    }
    float ss = 0.0f;
#pragma unroll
    for (int jj = 0; jj < 36; ++jj) ss += v[jj] * v[jj];
    const float s1 = 1.0f / (sqrtf(ss) + 3.6f);  // sz*0.1 = 36*0.1
    float ss2 = 0.0f;
#pragma unroll
    for (int jj = 0; jj < 36; ++jj) {
      v[jj] = fminf(v[jj] * s1, 0.2f);
      ss2 += v[jj] * v[jj];
    }
    const float s2 = 1.0f / (sqrtf(ss2) + 1e-3f);
    float4* dst = (float4*)(outF + (byg * 7 + bx) * 36);
#pragma unroll
    for (int q = 0; q < 9; ++q)
      dst[q] = make_float4(v[4 * q] * s2, v[4 * q + 1] * s2,
                           v[4 * q + 2] * s2, v[4 * q + 3] * s2);
  }
  if (half) {
    // zero the pad region [3780, 4096) and write passthrough outputs
    for (int i = 3780 + t; i < 4096; i += 256) outF[i] = 0.0f;
    if (t == 64) out[(size_t)B * 4096 + b] = (float)targets[b];
    if (t == 65) out[(size_t)B * 4096 + B + b] = (float)camid[b];
  }
}

extern "C" void kernel_launch(void* const* d_in, const int* in_sizes, int n_in,
                              void* d_out, int out_size, void* d_ws, size_t ws_size,
                              hipStream_t stream) {
  const float* images = (const float*)d_in[0];
  const int* targets = (const int*)d_in[1];
  const int* camid = (const int*)d_in[2];
  float* out = (float*)d_out;
  const int B = in_sizes[1];  // 512
  hipLaunchKernelGGL(hog_kernel, dim3(B * 2), dim3(256), 0, stream,
                     images, targets, camid, out, B);
}